// Round 1
// 1134.053 us; speedup vs baseline: 1.9086x; 1.9086x over previous
//
#include <hip/hip_runtime.h>
#include <stdint.h>

#define B_SZ   8192
#define IN_SZ  2048
#define HIDN   2048
#define KTOT   4096   // IN + HID
#define BM     128
#define BN     32     // within-gate cols per block (x4 gates = 128 A rows)
#define BK     32
#define MT     (B_SZ / BM)   // 64
#define NT     (HIDN / BN)   // 64
#define NKT    (KTOT / BK)   // 128 K-steps

typedef __attribute__((ext_vector_type(8))) short short8;
typedef __attribute__((ext_vector_type(8))) unsigned short ushort8;
typedef __attribute__((ext_vector_type(4))) float float4v;

static __device__ __forceinline__ float bf2f(uint16_t h) {
  union { uint32_t u; float f; } v; v.u = ((uint32_t)h) << 16; return v.f;
}
static __device__ __forceinline__ uint16_t f2bf(float f) {
  union { float f; uint32_t u; } v; v.f = f;
  uint32_t r = v.u + 0x7FFFu + ((v.u >> 16) & 1u);
  return (uint16_t)(r >> 16);
}
static __device__ __forceinline__ float sigmoidf_(float v) {
  return 1.f / (1.f + __expf(-v));
}
static __device__ __forceinline__ float tanhf_(float v) {
  return 1.f - 2.f / (1.f + __expf(2.f * v));
}

// load 8 logical elements starting at element index eidx, as bf16 bits
static __device__ __forceinline__ ushort8 load8(const void* base, size_t eidx, int isf32) {
  ushort8 r;
  if (isf32) {
    const float* p = (const float*)base + eidx;
    float4v a = *(const float4v*)p;
    float4v b = *(const float4v*)(p + 4);
    r[0] = f2bf(a[0]); r[1] = f2bf(a[1]); r[2] = f2bf(a[2]); r[3] = f2bf(a[3]);
    r[4] = f2bf(b[0]); r[5] = f2bf(b[1]); r[6] = f2bf(b[2]); r[7] = f2bf(b[3]);
  } else {
    r = *(const ushort8*)((const uint16_t*)base + eidx);
  }
  return r;
}

// async global->LDS, 16B per lane; dest is wave-uniform base + lane*16
static __device__ __forceinline__ void gll16(const void* g, void* l) {
  __builtin_amdgcn_global_load_lds(
      (const __attribute__((address_space(1))) uint32_t*)g,
      (__attribute__((address_space(3))) uint32_t*)l, 16, 0, 0);
}

// ---------------------------------------------------------------------------
// Kernel 0: dtype detect. bf16-packed x => low u16 of each u32 is a bf16 of
// N(0,1) (exp byte in [117,131] ~99.9%); f32 x => low u16 is uniform mantissa
// bits (~6% hit rate). flag: 0 = bf16, 1 = f32.
// ---------------------------------------------------------------------------
__global__ __launch_bounds__(64) void detect_kernel(const uint32_t* __restrict__ x,
                                                    int* __restrict__ flag) {
  const int lane = threadIdx.x;
  int cnt = 0;
  #pragma unroll
  for (int s = 0; s < 8; ++s) {
    uint32_t u = x[lane + s * 64];
    int e = (u >> 7) & 0xFF;
    int hit = (e >= 117 && e <= 131) ? 1 : 0;
    cnt += (int)__popcll(__ballot(hit));
  }
  if (lane == 0) *flag = (cnt < 256) ? 1 : 0;
}

// ---------------------------------------------------------------------------
// Kernel 1: transpose four gate weights [K][N] -> Wt[(n*4+g)][k] (bf16).
// Gate-interleaved rows so the fused kernel's 128-row A-tile is CONTIGUOUS
// in global memory (required for linear global_load_lds staging).
// ---------------------------------------------------------------------------
__global__ __launch_bounds__(256) void wtrans_kernel(
    const void* __restrict__ Wf, const void* __restrict__ Wi,
    const void* __restrict__ Wc, const void* __restrict__ Wo,
    uint16_t* __restrict__ Wt, const int* __restrict__ flagp)
{
  __shared__ uint16_t tile[64][33];  // [n][k], +1 pad
  const int isf32 = *flagp;
  const int k0 = blockIdx.x * 32;
  const int n0 = blockIdx.y * 64;
  const int g  = blockIdx.z;
  const void* W = (g == 0) ? Wf : (g == 1) ? Wi : (g == 2) ? Wc : Wo;
  const int tid = threadIdx.x;
  {
    const int r  = tid >> 3;        // k-local 0..31
    const int c8 = (tid & 7) * 8;   // n-local 0,8,..56
    ushort8 v = load8(W, (size_t)(k0 + r) * HIDN + n0 + c8, isf32);
    #pragma unroll
    for (int e = 0; e < 8; ++e) tile[c8 + e][r] = v[e];
  }
  __syncthreads();
  {
    const int n  = tid >> 2;        // 0..63
    const int kc = (tid & 3) * 8;   // 0,8,16,24
    ushort8 v;
    #pragma unroll
    for (int e = 0; e < 8; ++e) v[e] = tile[n][kc + e];
    *(ushort8*)(Wt + (size_t)((n0 + n) * 4 + g) * KTOT + k0 + kc) = v;
  }
}

// ---------------------------------------------------------------------------
// Kernel 2: one-shot cat = [x | h_prev] -> bf16 catB[B][KTOT].
// Removes the per-n-tile f32->bf16 repack (was done 64x redundantly) and
// enables global_load_lds staging in the GEMM.
// ---------------------------------------------------------------------------
__global__ __launch_bounds__(256) void catconv_kernel(
    const void* __restrict__ x, const void* __restrict__ h,
    uint16_t* __restrict__ catB, const int* __restrict__ flagp)
{
  const int isf32 = *flagp;
  const void* src = blockIdx.y ? h : x;
  const size_t t = (size_t)blockIdx.x * 256 + threadIdx.x;  // 8 elems/thread
  const int m  = (int)(t >> 8);          // 2048/8 = 256 chunks per row
  const int k8 = (int)(t & 255) * 8;
  ushort8 v = load8(src, (size_t)m * IN_SZ + k8, isf32);
  *(ushort8*)(catB + (size_t)m * KTOT + (size_t)blockIdx.y * IN_SZ + k8) = v;
}

// ---------------------------------------------------------------------------
// Kernel 3: fused 4-gate GEMM + LSTM epilogue, m97 structure:
//   double-buffered LDS, global_load_lds_dwordx4 prefetch of tile t+1 while
//   MFMAing tile t, ONE barrier per BK=32 K-step.
//   A = Wt rows (gate-interleaved n'), B = catB rows (m). D: col=lane&15 (m),
//   row=quad*4+reg (n' interleaved; gate = reg). Epilogue verbatim from the
//   verified kernel.
// LDS layout (bytes): A0 @0, B0 @8192, A1 @16384, B1 @24576, cpT @32768.
// ---------------------------------------------------------------------------
__global__ __launch_bounds__(256) void lstm_fused_kernel(
    const uint16_t* __restrict__ Wt, const uint16_t* __restrict__ catB,
    const void* __restrict__ cprev,
    const void* __restrict__ bfv, const void* __restrict__ biv,
    const void* __restrict__ bcv, const void* __restrict__ bov,
    void* __restrict__ outbase, const int* __restrict__ flagp)
{
  __shared__ __align__(16) uint16_t smem[20480];  // 40 KB
  uint16_t* cpT = smem + 16384;   // [128 m][32 n]

  const int isf32 = *flagp;
  const int tid  = threadIdx.x;
  const int lane = tid & 63;
  const int wave = tid >> 6;
  const int l15  = lane & 15;
  const int quad = lane >> 4;
  const int wn   = wave & 1;
  const int wm   = wave >> 1;

  // swizzled block -> (mtile, ntile)
  const int GRP = 8;
  const int bid = blockIdx.x;
  const int grp = bid / (GRP * NT);
  const int rem = bid % (GRP * NT);
  const int m0  = (grp * GRP + (rem % GRP)) * BM;
  const int n0  = (rem / GRP) * BN;

  // epilogue / cpT staging coords: thread covers tile bytes [off0+s*4096,+16)
  const int off0 = wave * 1024 + lane * 16;
  int rowS[2], q8S[2];
  #pragma unroll
  for (int s = 0; s < 2; ++s) {
    const int off = off0 + s * 4096;
    rowS[s] = off >> 6;
    q8S[s]  = ((off >> 4) & 3) * 8;
  }

  // stage c_prev tile into cpT (read only in epilogue)
  #pragma unroll
  for (int s = 0; s < 2; ++s) {
    ushort8 v = load8(cprev, (size_t)(m0 + rowS[s]) * HIDN + n0 + q8S[s], isf32);
    *(ushort8*)((char*)cpT + off0 + s * 4096) = v;
  }

  // --- staging setup: per-lane global src, wave-uniform LDS dst ---
  // wave w, slot s covers 16 rows: row = w*32 + s*16 + (lane>>2), 16B at (lane&3)*16
  const int srow = wave * 32 + (lane >> 2);
  const int scol = (lane & 3) * 8;   // elements
  const uint16_t* aS = Wt   + (size_t)(n0 * 4 + srow) * KTOT + scol;
  const uint16_t* bS = catB + (size_t)(m0 + srow) * KTOT + scol;
  const int dA = wave * 2048;          // LDS byte base (+ s*1024, + buf*16384)
  const int dB = 8192 + wave * 2048;

  // fragment read byte offsets (relative to current buffer base)
  int aOff[4], bOff[4];
  #pragma unroll
  for (int t = 0; t < 4; ++t) {
    aOff[t] = ((wn * 64 + t * 16 + l15) * BK + quad * 8) * 2;
    bOff[t] = 8192 + ((wm * 64 + t * 16 + l15) * BK + quad * 8) * 2;
  }

  float4v acc[4][4];
  #pragma unroll
  for (int i = 0; i < 4; ++i)
    #pragma unroll
    for (int j = 0; j < 4; ++j)
      acc[i][j] = {0.f, 0.f, 0.f, 0.f};

  auto kstep = [&](int cb) {
    short8 af[4], bf8[4];
    #pragma unroll
    for (int t = 0; t < 4; ++t) af[t]  = *(const short8*)((const char*)smem + cb + aOff[t]);
    #pragma unroll
    for (int t = 0; t < 4; ++t) bf8[t] = *(const short8*)((const char*)smem + cb + bOff[t]);
    #pragma unroll
    for (int i = 0; i < 4; ++i)
      #pragma unroll
      for (int j = 0; j < 4; ++j)
        acc[i][j] = __builtin_amdgcn_mfma_f32_16x16x32_bf16(af[i], bf8[j], acc[i][j], 0, 0, 0);
  };

  // prologue: stage k=0 into buf0; barrier drains vmcnt
  #pragma unroll
  for (int s = 0; s < 2; ++s) {
    gll16(aS + (size_t)s * 16 * KTOT, (char*)smem + dA + s * 1024);
    gll16(bS + (size_t)s * 16 * KTOT, (char*)smem + dB + s * 1024);
  }
  __syncthreads();

  int curb = 0;
  for (int t = 0; t < NKT - 1; ++t) {
    const int nxt = curb ^ 16384;
    const int kk = (t + 1) * BK;
    #pragma unroll
    for (int s = 0; s < 2; ++s) {
      gll16(aS + (size_t)s * 16 * KTOT + kk, (char*)smem + nxt + dA + s * 1024);
      gll16(bS + (size_t)s * 16 * KTOT + kk, (char*)smem + nxt + dB + s * 1024);
    }
    kstep(curb);
    __syncthreads();   // drains vmcnt (stage t+1 landed) + lgkm; guards reuse
    curb = nxt;
  }
  kstep(curb);         // last tile, no prefetch

  // ---- epilogue: compute h/c into registers ----
  // n' = wn*64 + i*16 + quad*4 + reg -> gate = reg, col nl = wn*16 + i*4 + quad
  float hv[4][4], cv[4][4];
  #pragma unroll
  for (int i = 0; i < 4; ++i) {
    const int nl = wn * 16 + i * 4 + quad;   // 0..31
    const int ng = n0 + nl;
    const float bfx = isf32 ? ((const float*)bfv)[ng] : bf2f(((const uint16_t*)bfv)[ng]);
    const float bix = isf32 ? ((const float*)biv)[ng] : bf2f(((const uint16_t*)biv)[ng]);
    const float bcx = isf32 ? ((const float*)bcv)[ng] : bf2f(((const uint16_t*)bcv)[ng]);
    const float box = isf32 ? ((const float*)bov)[ng] : bf2f(((const uint16_t*)bov)[ng]);
    #pragma unroll
    for (int j = 0; j < 4; ++j) {
      const int ml = wm * 64 + j * 16 + l15;  // 0..127
      float4v z = acc[i][j];
      const float ft  = sigmoidf_(z[0] + bfx);
      const float it  = sigmoidf_(z[1] + bix);
      const float cto = tanhf_(z[2] + bcx);
      const float ot  = sigmoidf_(z[3] + box);
      const float cp  = bf2f(cpT[ml * BN + nl]);
      cv[i][j] = cp * ft + it * cto;
      hv[i][j] = ot * tanhf_(cv[i][j]);
    }
  }

  __syncthreads();  // all fragment LDS reads done before tile reuse

  if (!isf32) {
    uint16_t* hout = (uint16_t*)outbase;
    uint16_t* cout = hout + (size_t)B_SZ * HIDN;
    uint16_t* hT = smem;          // [128][32] overlays A0
    uint16_t* cT = smem + 4096;   // overlays B0
    #pragma unroll
    for (int i = 0; i < 4; ++i) {
      const int nl = wn * 16 + i * 4 + quad;
      #pragma unroll
      for (int j = 0; j < 4; ++j) {
        const int ml = wm * 64 + j * 16 + l15;
        hT[ml * BN + nl] = f2bf(hv[i][j]);
        cT[ml * BN + nl] = f2bf(cv[i][j]);
      }
    }
    __syncthreads();
    #pragma unroll
    for (int s = 0; s < 2; ++s) {
      const int row = rowS[s], q8 = q8S[s];
      const size_t goff = (size_t)(m0 + row) * HIDN + n0 + q8;
      *(ushort8*)(hout + goff) = *(const ushort8*)(hT + row * BK + q8);
      *(ushort8*)(cout + goff) = *(const ushort8*)(cT + row * BK + q8);
    }
  } else {
    float* hout = (float*)outbase;
    float* cout = hout + (size_t)B_SZ * HIDN;
    float* fb = (float*)smem;   // 16 KB bounce (overlays A0+B0), [128][32] f32
    #pragma unroll
    for (int i = 0; i < 4; ++i) {
      const int nl = wn * 16 + i * 4 + quad;
      #pragma unroll
      for (int j = 0; j < 4; ++j) fb[(wm * 64 + j * 16 + l15) * BN + nl] = hv[i][j];
    }
    __syncthreads();
    #pragma unroll
    for (int s = 0; s < 4; ++s) {
      const int off = tid * 16 + s * 4096;        // bytes in 16 KB tile
      const int row = off >> 7;                   // 128 B per row (32 f32)
      const int c4  = (off >> 4) & 7;
      *(float4v*)(hout + (size_t)(m0 + row) * HIDN + n0 + c4 * 4) =
          *(const float4v*)((const char*)fb + off);
    }
    __syncthreads();
    #pragma unroll
    for (int i = 0; i < 4; ++i) {
      const int nl = wn * 16 + i * 4 + quad;
      #pragma unroll
      for (int j = 0; j < 4; ++j) fb[(wm * 64 + j * 16 + l15) * BN + nl] = cv[i][j];
    }
    __syncthreads();
    #pragma unroll
    for (int s = 0; s < 4; ++s) {
      const int off = tid * 16 + s * 4096;
      const int row = off >> 7;
      const int c4  = (off >> 4) & 7;
      *(float4v*)(cout + (size_t)(m0 + row) * HIDN + n0 + c4 * 4) =
          *(const float4v*)((const char*)fb + off);
    }
  }
}

extern "C" void kernel_launch(void* const* d_in, const int* in_sizes, int n_in,
                              void* d_out, int out_size, void* d_ws, size_t ws_size,
                              hipStream_t stream) {
  const void* x   = d_in[0];
  const void* h   = d_in[1];
  const void* c   = d_in[2];
  // d_in[3] = embedding_vec, ignored in vanilla mode
  const void* Wf  = d_in[4];
  const void* Wi  = d_in[5];
  const void* Wc  = d_in[6];
  const void* Wo  = d_in[7];
  const void* bf_ = d_in[8];
  const void* bi_ = d_in[9];
  const void* bc_ = d_in[10];
  const void* bo_ = d_in[11];

  int*      flag = (int*)d_ws;
  uint16_t* Wt   = (uint16_t*)((char*)d_ws + 256);                          // 64 MiB
  uint16_t* catB = (uint16_t*)((char*)d_ws + 256 + (size_t)64 * 1024 * 1024); // 64 MiB

  hipLaunchKernelGGL(detect_kernel, dim3(1), dim3(64), 0, stream,
                     (const uint32_t*)x, flag);
  hipLaunchKernelGGL(wtrans_kernel, dim3(KTOT / 32, HIDN / 64, 4), dim3(256), 0, stream,
                     Wf, Wi, Wc, Wo, Wt, flag);
  hipLaunchKernelGGL(catconv_kernel, dim3(B_SZ * IN_SZ / (8 * 256), 2, 1), dim3(256), 0, stream,
                     x, h, catB, flag);
  hipLaunchKernelGGL(lstm_fused_kernel, dim3(MT * NT), dim3(256), 0, stream,
                     Wt, catB, c, bf_, bi_, bc_, bo_, d_out, flag);
}

// Round 2
// 889.101 us; speedup vs baseline: 2.4344x; 1.2755x over previous
//
#include <hip/hip_runtime.h>
#include <stdint.h>

#define B_SZ   8192
#define IN_SZ  2048
#define HIDN   2048
#define KTOT   4096   // IN + HID
#define BKk    32
#define NKS    (KTOT / BKk)   // 128 K-steps
#define GRID_F 1024           // (8192/256) * (8192/256)

typedef __attribute__((ext_vector_type(8))) short short8;
typedef __attribute__((ext_vector_type(8))) unsigned short ushort8;
typedef __attribute__((ext_vector_type(4))) float float4v;

static __device__ __forceinline__ float bf2f(uint16_t h) {
  union { uint32_t u; float f; } v; v.u = ((uint32_t)h) << 16; return v.f;
}
static __device__ __forceinline__ uint16_t f2bf(float f) {
  union { float f; uint32_t u; } v; v.f = f;
  uint32_t r = v.u + 0x7FFFu + ((v.u >> 16) & 1u);
  return (uint16_t)(r >> 16);
}
static __device__ __forceinline__ float sigmoidf_(float v) {
  return 1.f / (1.f + __expf(-v));
}
static __device__ __forceinline__ float tanhf_(float v) {
  return 1.f - 2.f / (1.f + __expf(2.f * v));
}

static __device__ __forceinline__ ushort8 load8(const void* base, size_t eidx, int isf32) {
  ushort8 r;
  if (isf32) {
    const float* p = (const float*)base + eidx;
    float4v a = *(const float4v*)p;
    float4v b = *(const float4v*)(p + 4);
    r[0] = f2bf(a[0]); r[1] = f2bf(a[1]); r[2] = f2bf(a[2]); r[3] = f2bf(a[3]);
    r[4] = f2bf(b[0]); r[5] = f2bf(b[1]); r[6] = f2bf(b[2]); r[7] = f2bf(b[3]);
  } else {
    r = *(const ushort8*)((const uint16_t*)base + eidx);
  }
  return r;
}

// async global->LDS, 16B per lane; dest is wave-uniform base + lane*16
static __device__ __forceinline__ void gll16(const void* g, void* l) {
  __builtin_amdgcn_global_load_lds(
      (const __attribute__((address_space(1))) uint32_t*)g,
      (__attribute__((address_space(3))) uint32_t*)l, 16, 0, 0);
}

// raw barrier: no vmcnt drain (unlike __syncthreads). Compiler-level memory
// fences stop load/store motion across it; waitcnt discipline is manual.
static __device__ __forceinline__ void bar() {
  asm volatile("" ::: "memory");
  __builtin_amdgcn_s_barrier();
  asm volatile("" ::: "memory");
}

// ---------------------------------------------------------------------------
// Kernel 0: dtype detect (unchanged).
// ---------------------------------------------------------------------------
__global__ __launch_bounds__(64) void detect_kernel(const uint32_t* __restrict__ x,
                                                    int* __restrict__ flag) {
  const int lane = threadIdx.x;
  int cnt = 0;
  #pragma unroll
  for (int s = 0; s < 8; ++s) {
    uint32_t u = x[lane + s * 64];
    int e = (u >> 7) & 0xFF;
    int hit = (e >= 117 && e <= 131) ? 1 : 0;
    cnt += (int)__popcll(__ballot(hit));
  }
  if (lane == 0) *flag = (cnt < 256) ? 1 : 0;
}

// ---------------------------------------------------------------------------
// Kernel 1: transpose four gate weights [K][N] -> Wt[(n*4+g)][k] (unchanged).
// ---------------------------------------------------------------------------
__global__ __launch_bounds__(256) void wtrans_kernel(
    const void* __restrict__ Wf, const void* __restrict__ Wi,
    const void* __restrict__ Wc, const void* __restrict__ Wo,
    uint16_t* __restrict__ Wt, const int* __restrict__ flagp)
{
  __shared__ uint16_t tile[64][33];
  const int isf32 = *flagp;
  const int k0 = blockIdx.x * 32;
  const int n0 = blockIdx.y * 64;
  const int g  = blockIdx.z;
  const void* W = (g == 0) ? Wf : (g == 1) ? Wi : (g == 2) ? Wc : Wo;
  const int tid = threadIdx.x;
  {
    const int r  = tid >> 3;
    const int c8 = (tid & 7) * 8;
    ushort8 v = load8(W, (size_t)(k0 + r) * HIDN + n0 + c8, isf32);
    #pragma unroll
    for (int e = 0; e < 8; ++e) tile[c8 + e][r] = v[e];
  }
  __syncthreads();
  {
    const int n  = tid >> 2;
    const int kc = (tid & 3) * 8;
    ushort8 v;
    #pragma unroll
    for (int e = 0; e < 8; ++e) v[e] = tile[n][kc + e];
    *(ushort8*)(Wt + (size_t)((n0 + n) * 4 + g) * KTOT + k0 + kc) = v;
  }
}

// ---------------------------------------------------------------------------
// Kernel 2: cat = [x | h_prev] -> bf16 catB[B][KTOT] (unchanged).
// ---------------------------------------------------------------------------
__global__ __launch_bounds__(256) void catconv_kernel(
    const void* __restrict__ x, const void* __restrict__ h,
    uint16_t* __restrict__ catB, const int* __restrict__ flagp)
{
  const int isf32 = *flagp;
  const void* src = blockIdx.y ? h : x;
  const size_t t = (size_t)blockIdx.x * 256 + threadIdx.x;
  const int m  = (int)(t >> 8);
  const int k8 = (int)(t & 255) * 8;
  ushort8 v = load8(src, (size_t)m * IN_SZ + k8, isf32);
  *(ushort8*)(catB + (size_t)m * KTOT + (size_t)blockIdx.y * IN_SZ + k8) = v;
}

// ---------------------------------------------------------------------------
// Kernel 3: fused 4-gate GEMM + LSTM epilogue. 256x256 tile, BK=32, 512 thr
// (8 waves = 2 n'-halves x 4 m-quarters, per-wave 128x64 output).
//
// Schedule (T3+T4): ring of 4 LDS buffers (32 KiB each: A 16K + B 16K),
// prefetch lead 3 K-tiles via global_load_lds, ONE s_waitcnt vmcnt(8) per
// K-step (tail: 4,0), raw s_barrier (no drain). Invariants:
//   - step t reads buf[t&3]; tile t+3 staged into buf[(t+3)&3] (= buf of
//     tile t-1, whose reads finished before step t's first barrier).
//   - end-of-step vmcnt(8) leaves only the 2 newest tiles in flight =>
//     tile t+1 landed before its first ds_read.
// LDS swizzle (T2): st_16x32 within each 1024B subtile (16 rows x 32 bf16):
//   byte ^= ((byte>>9)&1)<<5, applied on BOTH the inverse-swizzled global
//   source (gll dest is linear) and the ds_read address (rule 21).
// T5: setprio(1) around each 16-MFMA cluster.
// ---------------------------------------------------------------------------
extern "C" __global__ __launch_bounds__(512, 2) void lstm_fused_kernel(
    const uint16_t* __restrict__ Wt, const uint16_t* __restrict__ catB,
    const void* __restrict__ cprev,
    const void* __restrict__ bfv, const void* __restrict__ biv,
    const void* __restrict__ bcv, const void* __restrict__ bov,
    void* __restrict__ outbase, const int* __restrict__ flagp)
{
  extern __shared__ __align__(16) char ldsbuf[];   // 128 KiB dynamic

  const int isf32 = *flagp;
  const int tid  = threadIdx.x;        // 0..511
  const int lane = tid & 63;
  const int wave = tid >> 6;           // 0..7
  const int l15  = lane & 15;
  const int quad = lane >> 4;
  const int wr   = wave >> 2;          // n'-half (0,1): 128 Wt rows
  const int wc   = wave & 3;           // m-quarter (0..3): 64 catB rows

  // XCD-chunked swizzle: bid%8 = XCD; each XCD gets 4 n-tiles x 32 m-tiles.
  const int bid = blockIdx.x;
  const int xcd = bid & 7, loc = bid >> 3;        // loc 0..127
  const int nt  = xcd * 4 + (loc & 3);            // 0..31
  const int mt  = loc >> 2;                       // 0..31
  const int mB  = mt * 256;                       // catB row base
  const int nB  = nt * 256;                       // Wt row base (n' units)
  const int nb4 = nt * 64;                        // gate-col base

  // ---- staging: lane covers 16B at linear LDS offset (s*8192+wave*1024+lane*16)
  // inverse st_16x32 swizzle in closed form:
  //   row = (s*8+wave)*16 + (lane>>2); col8 = ((lane&3) ^ ((lane>>5)<<1))*8
  const int srow = lane >> 2;
  const int scol = ((lane & 3) ^ ((lane >> 5) << 1)) * 8;
  const uint16_t* aSrc[2];
  const uint16_t* bSrc[2];
  #pragma unroll
  for (int s = 0; s < 2; ++s) {
    aSrc[s] = Wt   + (size_t)(nB + (s * 8 + wave) * 16 + srow) * KTOT + scol;
    bSrc[s] = catB + (size_t)(mB + (s * 8 + wave) * 16 + srow) * KTOT + scol;
  }

  // ---- fragment read offsets (swizzled): subtile rg = row>>4, 1024B each
  int offA[8], offB[4];
  #pragma unroll
  for (int i = 0; i < 8; ++i) {
    const int b = (wr * 8 + i) * 1024 + l15 * 64 + quad * 16;
    offA[i] = b ^ (((l15 >> 3) & 1) << 5);
  }
  #pragma unroll
  for (int j = 0; j < 4; ++j) {
    const int b = (wc * 4 + j) * 1024 + l15 * 64 + quad * 16;
    offB[j] = 16384 + (b ^ (((l15 >> 3) & 1) << 5));
  }

  float4v acc[8][4];
  #pragma unroll
  for (int i = 0; i < 8; ++i)
    #pragma unroll
    for (int j = 0; j < 4; ++j)
      acc[i][j] = {0.f, 0.f, 0.f, 0.f};

  // prologue: stage tiles 0,1,2 (12 gll per wave); wait tile 0 (oldest 4)
  #pragma unroll
  for (int tt = 0; tt < 3; ++tt) {
    const size_t kk = (size_t)tt * BKk;
    const int bb = (tt & 3) * 32768 + wave * 1024;
    gll16(aSrc[0] + kk, ldsbuf + bb);
    gll16(aSrc[1] + kk, ldsbuf + bb + 8192);
    gll16(bSrc[0] + kk, ldsbuf + bb + 16384);
    gll16(bSrc[1] + kk, ldsbuf + bb + 16384 + 8192);
  }
  asm volatile("s_waitcnt vmcnt(8)" ::: "memory");
  bar();

#define KSTEP(T, DO_STAGE, VMSTR)                                              \
  {                                                                            \
    const int bb = ((T) & 3) * 32768;                                          \
    short8 af[4], bfr[4];                                                      \
    _Pragma("unroll")                                                          \
    for (int j = 0; j < 4; ++j)                                                \
      bfr[j] = *(const short8*)(ldsbuf + bb + offB[j]);                        \
    _Pragma("unroll")                                                          \
    for (int ii = 0; ii < 4; ++ii)                                             \
      af[ii] = *(const short8*)(ldsbuf + bb + offA[ii]);                       \
    if (DO_STAGE) {                                                            \
      const size_t kk = (size_t)((T) + 3) * BKk;                               \
      const int sb = (((T) + 3) & 3) * 32768 + wave * 1024;                    \
      gll16(aSrc[0] + kk, ldsbuf + sb);                                        \
      gll16(aSrc[1] + kk, ldsbuf + sb + 8192);                                 \
    }                                                                          \
    bar();                                                                     \
    __builtin_amdgcn_s_setprio(1);                                             \
    _Pragma("unroll")                                                          \
    for (int ii = 0; ii < 4; ++ii)                                             \
      _Pragma("unroll")                                                        \
      for (int j = 0; j < 4; ++j)                                              \
        acc[ii][j] = __builtin_amdgcn_mfma_f32_16x16x32_bf16(                  \
            af[ii], bfr[j], acc[ii][j], 0, 0, 0);                              \
    __builtin_amdgcn_s_setprio(0);                                             \
    bar();                                                                     \
    _Pragma("unroll")                                                          \
    for (int ii = 0; ii < 4; ++ii)                                             \
      af[ii] = *(const short8*)(ldsbuf + bb + offA[4 + ii]);                   \
    if (DO_STAGE) {                                                            \
      const size_t kk = (size_t)((T) + 3) * BKk;                               \
      const int sb = (((T) + 3) & 3) * 32768 + 16384 + wave * 1024;            \
      gll16(bSrc[0] + kk, ldsbuf + sb);                                        \
      gll16(bSrc[1] + kk, ldsbuf + sb + 8192);                                 \
    }                                                                          \
    asm volatile("s_waitcnt " VMSTR ::: "memory");                             \
    bar();                                                                     \
    __builtin_amdgcn_s_setprio(1);                                             \
    _Pragma("unroll")                                                          \
    for (int ii = 0; ii < 4; ++ii)                                             \
      _Pragma("unroll")                                                        \
      for (int j = 0; j < 4; ++j)                                              \
        acc[4 + ii][j] = __builtin_amdgcn_mfma_f32_16x16x32_bf16(              \
            af[ii], bfr[j], acc[4 + ii][j], 0, 0, 0);                          \
    __builtin_amdgcn_s_setprio(0);                                             \
    bar();                                                                     \
  }

  for (int t = 0; t < NKS - 3; ++t) KSTEP(t, 1, "vmcnt(8)");
  KSTEP(NKS - 3, 0, "vmcnt(4)");
  KSTEP(NKS - 2, 0, "vmcnt(0)");
  KSTEP(NKS - 1, 0, "vmcnt(0)");
#undef KSTEP

  // ---- epilogue ----
  // D layout per MFMA: col = l15 (m-frag), row = quad*4+reg (n'-frag).
  // n' = nB + wr*128 + i*16 + quad*4 + reg; gate = reg; n = nb4 + wr*32 + i*4 + quad
  // m  = mB + wc*64 + j*16 + l15
  #pragma unroll
  for (int i = 0; i < 8; ++i) {
    const int ng = nb4 + wr * 32 + i * 4 + quad;   // 0..2047
    const float bfx = isf32 ? ((const float*)bfv)[ng] : bf2f(((const uint16_t*)bfv)[ng]);
    const float bix = isf32 ? ((const float*)biv)[ng] : bf2f(((const uint16_t*)biv)[ng]);
    const float bcx = isf32 ? ((const float*)bcv)[ng] : bf2f(((const uint16_t*)bcv)[ng]);
    const float box = isf32 ? ((const float*)bov)[ng] : bf2f(((const uint16_t*)bov)[ng]);
    #pragma unroll
    for (int j = 0; j < 4; ++j) {
      const int mg = mB + wc * 64 + j * 16 + l15;
      float4v z = acc[i][j];
      const float ft  = sigmoidf_(z[0] + bfx);
      const float it  = sigmoidf_(z[1] + bix);
      const float cto = tanhf_(z[2] + bcx);
      const float ot  = sigmoidf_(z[3] + box);
      const float cp  = isf32 ? ((const float*)cprev)[(size_t)mg * HIDN + ng]
                              : bf2f(((const uint16_t*)cprev)[(size_t)mg * HIDN + ng]);
      const float cvv = cp * ft + it * cto;
      acc[i][j][0] = ot * tanhf_(cvv);   // h
      acc[i][j][1] = cvv;                // c
    }
  }
  // all LDS reads of the K-loop completed before its final barrier -> safe reuse

  if (!isf32) {
    uint16_t* hout = (uint16_t*)outbase;
    uint16_t* cout = hout + (size_t)B_SZ * HIDN;
    uint16_t* hb = (uint16_t*)ldsbuf;             // [256][64]
    uint16_t* cb = (uint16_t*)(ldsbuf + 32768);
    #pragma unroll
    for (int i = 0; i < 8; ++i) {
      const int ncl = wr * 32 + i * 4 + quad;
      #pragma unroll
      for (int j = 0; j < 4; ++j) {
        const int ml = wc * 64 + j * 16 + l15;
        hb[ml * 64 + ncl] = f2bf(acc[i][j][0]);
        cb[ml * 64 + ncl] = f2bf(acc[i][j][1]);
      }
    }
    bar();
    #pragma unroll
    for (int s = 0; s < 4; ++s) {
      const int off = tid * 16 + s * 8192;        // within 32 KiB
      const int row = off >> 7;                   // 128 B per row (64 bf16)
      const int c8  = (off >> 4) & 7;
      const size_t g = (size_t)(mB + row) * HIDN + nb4 + c8 * 8;
      *(ushort8*)(hout + g) = *(const ushort8*)(ldsbuf + off);
      *(ushort8*)(cout + g) = *(const ushort8*)(ldsbuf + 32768 + off);
    }
  } else {
    float* hout = (float*)outbase;
    float* cout = hout + (size_t)B_SZ * HIDN;
    float* fbH = (float*)ldsbuf;                  // [256][64] f32 = 64 KiB
    float* fbC = (float*)(ldsbuf + 65536);
    #pragma unroll
    for (int i = 0; i < 8; ++i) {
      const int ncl = wr * 32 + i * 4 + quad;
      #pragma unroll
      for (int j = 0; j < 4; ++j) {
        const int ml = wc * 64 + j * 16 + l15;
        fbH[ml * 64 + ncl] = acc[i][j][0];
        fbC[ml * 64 + ncl] = acc[i][j][1];
      }
    }
    bar();
    #pragma unroll
    for (int s = 0; s < 8; ++s) {
      const int off = tid * 16 + s * 8192;        // within 64 KiB
      const int row = off >> 8;                   // 256 B per row (64 f32)
      const int c4  = (off >> 4) & 15;
      const size_t g = (size_t)(mB + row) * HIDN + nb4 + c4 * 4;
      *(float4v*)(hout + g) = *(const float4v*)(ldsbuf + off);
      *(float4v*)(cout + g) = *(const float4v*)(ldsbuf + 65536 + off);
    }
  }
}

extern "C" void kernel_launch(void* const* d_in, const int* in_sizes, int n_in,
                              void* d_out, int out_size, void* d_ws, size_t ws_size,
                              hipStream_t stream) {
  const void* x   = d_in[0];
  const void* h   = d_in[1];
  const void* c   = d_in[2];
  // d_in[3] = embedding_vec, ignored in vanilla mode
  const void* Wf  = d_in[4];
  const void* Wi  = d_in[5];
  const void* Wc  = d_in[6];
  const void* Wo  = d_in[7];
  const void* bf_ = d_in[8];
  const void* bi_ = d_in[9];
  const void* bc_ = d_in[10];
  const void* bo_ = d_in[11];

  int*      flag = (int*)d_ws;
  uint16_t* Wt   = (uint16_t*)((char*)d_ws + 256);                            // 64 MiB
  uint16_t* catB = (uint16_t*)((char*)d_ws + 256 + (size_t)64 * 1024 * 1024); // 64 MiB

  static int lds_configured = 0;
  if (!lds_configured) {
    hipFuncSetAttribute((const void*)lstm_fused_kernel,
                        hipFuncAttributeMaxDynamicSharedMemorySize, 131072);
    lds_configured = 1;
  }

  hipLaunchKernelGGL(detect_kernel, dim3(1), dim3(64), 0, stream,
                     (const uint32_t*)x, flag);
  hipLaunchKernelGGL(wtrans_kernel, dim3(KTOT / 32, HIDN / 64, 4), dim3(256), 0, stream,
                     Wf, Wi, Wc, Wo, Wt, flag);
  hipLaunchKernelGGL(catconv_kernel, dim3(B_SZ * IN_SZ / (8 * 256), 2, 1), dim3(256), 0, stream,
                     x, h, catB, flag);
  hipLaunchKernelGGL(lstm_fused_kernel, dim3(GRID_F), dim3(512), 131072, stream,
                     Wt, catB, c, bf_, bi_, bc_, bo_, d_out, flag);
}

// Round 3
// 875.724 us; speedup vs baseline: 2.4716x; 1.0153x over previous
//
#include <hip/hip_runtime.h>
#include <stdint.h>

#define B_SZ   8192
#define IN_SZ  2048
#define HIDN   2048
#define KTOT   4096   // IN + HID
#define BKk    32
#define NKS    (KTOT / BKk)   // 128 K-steps
#define GRID_F 1024           // (8192/256) * (8192/256)

typedef __attribute__((ext_vector_type(8))) short short8;
typedef __attribute__((ext_vector_type(8))) unsigned short ushort8;
typedef __attribute__((ext_vector_type(4))) float float4v;

static __device__ __forceinline__ float bf2f(uint16_t h) {
  union { uint32_t u; float f; } v; v.u = ((uint32_t)h) << 16; return v.f;
}
static __device__ __forceinline__ uint16_t f2bf(float f) {
  union { float f; uint32_t u; } v; v.f = f;
  uint32_t r = v.u + 0x7FFFu + ((v.u >> 16) & 1u);
  return (uint16_t)(r >> 16);
}
static __device__ __forceinline__ float sigmoidf_(float v) {
  return 1.f / (1.f + __expf(-v));
}
static __device__ __forceinline__ float tanhf_(float v) {
  return 1.f - 2.f / (1.f + __expf(2.f * v));
}

static __device__ __forceinline__ ushort8 load8(const void* base, size_t eidx, int isf32) {
  ushort8 r;
  if (isf32) {
    const float* p = (const float*)base + eidx;
    float4v a = *(const float4v*)p;
    float4v b = *(const float4v*)(p + 4);
    r[0] = f2bf(a[0]); r[1] = f2bf(a[1]); r[2] = f2bf(a[2]); r[3] = f2bf(a[3]);
    r[4] = f2bf(b[0]); r[5] = f2bf(b[1]); r[6] = f2bf(b[2]); r[7] = f2bf(b[3]);
  } else {
    r = *(const ushort8*)((const uint16_t*)base + eidx);
  }
  return r;
}

// async global->LDS, 16B per lane; dest is wave-uniform base + lane*16
static __device__ __forceinline__ void gll16(const void* g, void* l) {
  __builtin_amdgcn_global_load_lds(
      (const __attribute__((address_space(1))) uint32_t*)g,
      (__attribute__((address_space(3))) uint32_t*)l, 16, 0, 0);
}

// raw barrier: no vmcnt/lgkm drain. Used ONLY in the K-loop where the only
// cross-wave LDS writers are global_load_lds DMAs ordered by counted vmcnt.
static __device__ __forceinline__ void bar() {
  asm volatile("" ::: "memory");
  __builtin_amdgcn_s_barrier();
  asm volatile("" ::: "memory");
}

// ---------------------------------------------------------------------------
// Kernel 0: dtype detect (unchanged).
// ---------------------------------------------------------------------------
__global__ __launch_bounds__(64) void detect_kernel(const uint32_t* __restrict__ x,
                                                    int* __restrict__ flag) {
  const int lane = threadIdx.x;
  int cnt = 0;
  #pragma unroll
  for (int s = 0; s < 8; ++s) {
    uint32_t u = x[lane + s * 64];
    int e = (u >> 7) & 0xFF;
    int hit = (e >= 117 && e <= 131) ? 1 : 0;
    cnt += (int)__popcll(__ballot(hit));
  }
  if (lane == 0) *flag = (cnt < 256) ? 1 : 0;
}

// ---------------------------------------------------------------------------
// Kernel 1: transpose four gate weights [K][N] -> Wt[(n*4+g)][k] (bf16), v2.
// One block = ALL 4 gates x [64 n][128 k]. Write phase emits 256B runs over
// CONSECUTIVE Wt rows (np = n*4+g matches the gate-interleaved row order),
// rows strided 8KB (vs 64B runs @32KB before -- DRAM-channel friendly).
// LDS transpose tile is chunk-XOR swizzled (phys_kchunk = kchunk ^ (n>>3)),
// which makes the scalar scatter conflict-free with NO padding (64KB exact).
// ---------------------------------------------------------------------------
__global__ __launch_bounds__(256) void wtrans_kernel(
    const void* __restrict__ Wf, const void* __restrict__ Wi,
    const void* __restrict__ Wc, const void* __restrict__ Wo,
    uint16_t* __restrict__ Wt, const int* __restrict__ flagp)
{
  __shared__ uint16_t tile[4 * 64 * 128];   // 64 KB, [g*64+n][128 k] swizzled
  const int isf32 = *flagp;
  const int k0 = blockIdx.x * 128;
  const int n0 = blockIdx.y * 64;
  const int tid = threadIdx.x;
  const void* Wg4[4] = {Wf, Wi, Wc, Wo};

  // read: flat over 4 g x 128 k x 8 n-chunks = 4096 loads; 16 per thread.
  // lanes: c=flat&7 (8 x 8 n = 256B contiguous), r=k-row (8 per wave).
  #pragma unroll
  for (int s = 0; s < 16; ++s) {
    const int flat = s * 256 + tid;
    const int g = flat >> 10;
    const int r = (flat >> 3) & 127;      // k-local
    const int c = flat & 7;               // n-chunk
    ushort8 v = load8(Wg4[g], (size_t)(k0 + r) * HIDN + n0 + c * 8, isf32);
    // transposed store: row = g*64 + (c*8+e); f(row-local-n) = c (e<8).
    // phys k-elem = (r&7) + 8*((r>>3) ^ c)  -- same for all e.
    uint16_t* trow = tile + (g * 64 + c * 8) * 128 + (r & 7) + 8 * ((r >> 3) ^ c);
    #pragma unroll
    for (int e = 0; e < 8; ++e) trow[e * 128] = v[e];
  }
  __syncthreads();

  // write: flat over 256 np x 16 k-chunks; lanes: kc 0..15 (256B run of one
  // row), np -> 4 consecutive Wt rows per wave.
  #pragma unroll
  for (int s = 0; s < 16; ++s) {
    const int flat = s * 256 + tid;
    const int kc = flat & 15;             // k-chunk (8 elems)
    const int np = flat >> 4;             // 0..255 == local Wt row
    const int n  = np >> 2;
    ushort8 v = *(const ushort8*)(tile + (np & 3) * 8192 + n * 128 +
                                  ((kc ^ (n >> 3)) * 8));
    *(ushort8*)(Wt + (size_t)(n0 * 4 + np) * KTOT + k0 + kc * 8) = v;
  }
}

// ---------------------------------------------------------------------------
// Kernel 2: cat = [x | h_prev] -> bf16 catB[B][KTOT] (unchanged).
// ---------------------------------------------------------------------------
__global__ __launch_bounds__(256) void catconv_kernel(
    const void* __restrict__ x, const void* __restrict__ h,
    uint16_t* __restrict__ catB, const int* __restrict__ flagp)
{
  const int isf32 = *flagp;
  const void* src = blockIdx.y ? h : x;
  const size_t t = (size_t)blockIdx.x * 256 + threadIdx.x;
  const int m  = (int)(t >> 8);
  const int k8 = (int)(t & 255) * 8;
  ushort8 v = load8(src, (size_t)m * IN_SZ + k8, isf32);
  *(ushort8*)(catB + (size_t)m * KTOT + (size_t)blockIdx.y * IN_SZ + k8) = v;
}

// ---------------------------------------------------------------------------
// Kernel 3: fused 4-gate GEMM + LSTM epilogue. 256x256 tile, BK=32, 512 thr.
// Ring-4 LDS dbuf + counted vmcnt (T3+T4), setprio (T5), XCD-chunked grid (T1).
// LDS swizzle (T2, FULL-RANK v2): within each 1024B subtile (16 rows x 4
// 16B-slots), slot ^= (row>>1)&3  (byte ^= ((byte>>7)&3)<<4). Each
// quarter-wave's 16 ds_read_b128 lanes then hit each 8-bank-group exactly
// twice (2-way = free, m136) -- the previous bit5-only swizzle left 4-way.
// Applied as the same involution on the gll16 global SOURCE (LDS dest stays
// linear) and on the fragment-read address (rule 21).
// ---------------------------------------------------------------------------
extern "C" __global__ __launch_bounds__(512, 2) void lstm_fused_kernel(
    const uint16_t* __restrict__ Wt, const uint16_t* __restrict__ catB,
    const void* __restrict__ cprev,
    const void* __restrict__ bfv, const void* __restrict__ biv,
    const void* __restrict__ bcv, const void* __restrict__ bov,
    void* __restrict__ outbase, const int* __restrict__ flagp)
{
  extern __shared__ __align__(16) char ldsbuf[];   // 128 KiB dynamic

  const int isf32 = *flagp;
  const int tid  = threadIdx.x;        // 0..511
  const int lane = tid & 63;
  const int wave = tid >> 6;           // 0..7
  const int l15  = lane & 15;
  const int quad = lane >> 4;
  const int wr   = wave >> 2;          // n'-half (0,1): 128 Wt rows
  const int wc   = wave & 3;           // m-quarter (0..3): 64 catB rows

  // XCD-chunked swizzle: bid%8 = XCD; each XCD gets 4 n-tiles x 32 m-tiles.
  const int bid = blockIdx.x;
  const int xcd = bid & 7, loc = bid >> 3;        // loc 0..127
  const int nt  = xcd * 4 + (loc & 3);            // 0..31
  const int mt  = loc >> 2;                       // 0..31
  const int mB  = mt * 256;                       // catB row base
  const int nB  = nt * 256;                       // Wt row base (n' units)
  const int nb4 = nt * 64;                        // gate-col base

  // ---- staging: lane covers 16B at linear LDS offset (wave*1024 + lane*16)
  // row = lane>>2 (in 16-row subtile), phys slot = lane&3; inverse swizzle:
  // source slot = (lane&3) ^ ((row>>1)&3) = (lane&3) ^ ((lane>>3)&3)
  const int srow = lane >> 2;
  const int scol = ((lane & 3) ^ ((lane >> 3) & 3)) * 8;
  const uint16_t* aSrc[2];
  const uint16_t* bSrc[2];
  #pragma unroll
  for (int s = 0; s < 2; ++s) {
    aSrc[s] = Wt   + (size_t)(nB + (s * 8 + wave) * 16 + srow) * KTOT + scol;
    bSrc[s] = catB + (size_t)(mB + (s * 8 + wave) * 16 + srow) * KTOT + scol;
  }

  // ---- fragment read offsets (full-rank swizzle)
  const int rswz = (quad ^ ((l15 >> 1) & 3)) << 4;
  int offA[8], offB[4];
  #pragma unroll
  for (int i = 0; i < 8; ++i)
    offA[i] = (wr * 8 + i) * 1024 + l15 * 64 + rswz;
  #pragma unroll
  for (int j = 0; j < 4; ++j)
    offB[j] = 16384 + (wc * 4 + j) * 1024 + l15 * 64 + rswz;

  float4v acc[8][4];
  #pragma unroll
  for (int i = 0; i < 8; ++i)
    #pragma unroll
    for (int j = 0; j < 4; ++j)
      acc[i][j] = {0.f, 0.f, 0.f, 0.f};

  // prologue: stage tiles 0,1,2 (12 gll per wave); wait tile 0 (oldest 4)
  #pragma unroll
  for (int tt = 0; tt < 3; ++tt) {
    const size_t kk = (size_t)tt * BKk;
    const int bb = (tt & 3) * 32768 + wave * 1024;
    gll16(aSrc[0] + kk, ldsbuf + bb);
    gll16(aSrc[1] + kk, ldsbuf + bb + 8192);
    gll16(bSrc[0] + kk, ldsbuf + bb + 16384);
    gll16(bSrc[1] + kk, ldsbuf + bb + 16384 + 8192);
  }
  asm volatile("s_waitcnt vmcnt(8)" ::: "memory");
  bar();

#define KSTEP(T, DO_STAGE, VMSTR)                                              \
  {                                                                            \
    const int bb = ((T) & 3) * 32768;                                          \
    short8 af[4], bfr[4];                                                      \
    _Pragma("unroll")                                                          \
    for (int j = 0; j < 4; ++j)                                                \
      bfr[j] = *(const short8*)(ldsbuf + bb + offB[j]);                        \
    _Pragma("unroll")                                                          \
    for (int ii = 0; ii < 4; ++ii)                                             \
      af[ii] = *(const short8*)(ldsbuf + bb + offA[ii]);                       \
    if (DO_STAGE) {                                                            \
      const size_t kk = (size_t)((T) + 3) * BKk;                               \
      const int sb = (((T) + 3) & 3) * 32768 + wave * 1024;                    \
      gll16(aSrc[0] + kk, ldsbuf + sb);                                        \
      gll16(aSrc[1] + kk, ldsbuf + sb + 8192);                                 \
    }                                                                          \
    bar();                                                                     \
    __builtin_amdgcn_s_setprio(1);                                             \
    _Pragma("unroll")                                                          \
    for (int ii = 0; ii < 4; ++ii)                                             \
      _Pragma("unroll")                                                        \
      for (int j = 0; j < 4; ++j)                                              \
        acc[ii][j] = __builtin_amdgcn_mfma_f32_16x16x32_bf16(                  \
            af[ii], bfr[j], acc[ii][j], 0, 0, 0);                              \
    __builtin_amdgcn_s_setprio(0);                                             \
    bar();                                                                     \
    _Pragma("unroll")                                                          \
    for (int ii = 0; ii < 4; ++ii)                                             \
      af[ii] = *(const short8*)(ldsbuf + bb + offA[4 + ii]);                   \
    if (DO_STAGE) {                                                            \
      const size_t kk = (size_t)((T) + 3) * BKk;                               \
      const int sb = (((T) + 3) & 3) * 32768 + 16384 + wave * 1024;            \
      gll16(bSrc[0] + kk, ldsbuf + sb);                                        \
      gll16(bSrc[1] + kk, ldsbuf + sb + 8192);                                 \
    }                                                                          \
    asm volatile("s_waitcnt " VMSTR ::: "memory");                             \
    bar();                                                                     \
    __builtin_amdgcn_s_setprio(1);                                             \
    _Pragma("unroll")                                                          \
    for (int ii = 0; ii < 4; ++ii)                                             \
      _Pragma("unroll")                                                        \
      for (int j = 0; j < 4; ++j)                                              \
        acc[4 + ii][j] = __builtin_amdgcn_mfma_f32_16x16x32_bf16(              \
            af[ii], bfr[j], acc[4 + ii][j], 0, 0, 0);                          \
    __builtin_amdgcn_s_setprio(0);                                             \
    bar();                                                                     \
  }

  for (int t = 0; t < NKS - 3; ++t) KSTEP(t, 1, "vmcnt(8)");
  KSTEP(NKS - 3, 0, "vmcnt(4)");
  KSTEP(NKS - 2, 0, "vmcnt(0)");
  KSTEP(NKS - 1, 0, "vmcnt(0)");
#undef KSTEP

  // ---- epilogue ----
  // n' = nB + wr*128 + i*16 + quad*4 + reg; gate = reg; n = nb4 + wr*32 + i*4 + quad
  // m  = mB + wc*64 + j*16 + l15
  #pragma unroll
  for (int i = 0; i < 8; ++i) {
    const int ng = nb4 + wr * 32 + i * 4 + quad;   // 0..2047
    const float bfx = isf32 ? ((const float*)bfv)[ng] : bf2f(((const uint16_t*)bfv)[ng]);
    const float bix = isf32 ? ((const float*)biv)[ng] : bf2f(((const uint16_t*)biv)[ng]);
    const float bcx = isf32 ? ((const float*)bcv)[ng] : bf2f(((const uint16_t*)bcv)[ng]);
    const float box = isf32 ? ((const float*)bov)[ng] : bf2f(((const uint16_t*)bov)[ng]);
    #pragma unroll
    for (int j = 0; j < 4; ++j) {
      const int mg = mB + wc * 64 + j * 16 + l15;
      float4v z = acc[i][j];
      const float ft  = sigmoidf_(z[0] + bfx);
      const float it  = sigmoidf_(z[1] + bix);
      const float cto = tanhf_(z[2] + bcx);
      const float ot  = sigmoidf_(z[3] + box);
      const float cp  = isf32 ? ((const float*)cprev)[(size_t)mg * HIDN + ng]
                              : bf2f(((const uint16_t*)cprev)[(size_t)mg * HIDN + ng]);
      const float cvv = cp * ft + it * cto;
      acc[i][j][0] = ot * tanhf_(cvv);   // h
      acc[i][j][1] = cvv;                // c
    }
  }

  if (!isf32) {
    uint16_t* hout = (uint16_t*)outbase;
    uint16_t* cout = hout + (size_t)B_SZ * HIDN;
    uint16_t* hb = (uint16_t*)ldsbuf;             // [256][64]
    uint16_t* cb = (uint16_t*)(ldsbuf + 32768);
    #pragma unroll
    for (int i = 0; i < 8; ++i) {
      const int ncl = wr * 32 + i * 4 + quad;
      #pragma unroll
      for (int j = 0; j < 4; ++j) {
        const int ml = wc * 64 + j * 16 + l15;
        hb[ml * 64 + ncl] = f2bf(acc[i][j][0]);
        cb[ml * 64 + ncl] = f2bf(acc[i][j][1]);
      }
    }
    __syncthreads();   // full drain: ds_writes must be visible cross-wave
    #pragma unroll
    for (int s = 0; s < 4; ++s) {
      const int off = tid * 16 + s * 8192;        // within 32 KiB
      const int row = off >> 7;                   // 128 B per row (64 bf16)
      const int c8  = (off >> 4) & 7;
      const size_t g = (size_t)(mB + row) * HIDN + nb4 + c8 * 8;
      *(ushort8*)(hout + g) = *(const ushort8*)(ldsbuf + off);
      *(ushort8*)(cout + g) = *(const ushort8*)(ldsbuf + 32768 + off);
    }
  } else {
    float* hout = (float*)outbase;
    float* cout = hout + (size_t)B_SZ * HIDN;
    float* fbH = (float*)ldsbuf;                  // [256][64] f32 = 64 KiB
    float* fbC = (float*)(ldsbuf + 65536);
    #pragma unroll
    for (int i = 0; i < 8; ++i) {
      const int ncl = wr * 32 + i * 4 + quad;
      #pragma unroll
      for (int j = 0; j < 4; ++j) {
        const int ml = wc * 64 + j * 16 + l15;
        fbH[ml * 64 + ncl] = acc[i][j][0];
        fbC[ml * 64 + ncl] = acc[i][j][1];
      }
    }
    __syncthreads();   // full drain: ds_writes must be visible cross-wave
    #pragma unroll
    for (int s = 0; s < 8; ++s) {
      const int off = tid * 16 + s * 8192;        // within 64 KiB
      const int row = off >> 8;                   // 256 B per row (64 f32)
      const int c4  = (off >> 4) & 15;
      const size_t g = (size_t)(mB + row) * HIDN + nb4 + c4 * 4;
      *(float4v*)(hout + g) = *(const float4v*)(ldsbuf + off);
      *(float4v*)(cout + g) = *(const float4v*)(ldsbuf + 65536 + off);
    }
  }
}

extern "C" void kernel_launch(void* const* d_in, const int* in_sizes, int n_in,
                              void* d_out, int out_size, void* d_ws, size_t ws_size,
                              hipStream_t stream) {
  const void* x   = d_in[0];
  const void* h   = d_in[1];
  const void* c   = d_in[2];
  // d_in[3] = embedding_vec, ignored in vanilla mode
  const void* Wf  = d_in[4];
  const void* Wi  = d_in[5];
  const void* Wc  = d_in[6];
  const void* Wo  = d_in[7];
  const void* bf_ = d_in[8];
  const void* bi_ = d_in[9];
  const void* bc_ = d_in[10];
  const void* bo_ = d_in[11];

  int*      flag = (int*)d_ws;
  uint16_t* Wt   = (uint16_t*)((char*)d_ws + 256);                            // 64 MiB
  uint16_t* catB = (uint16_t*)((char*)d_ws + 256 + (size_t)64 * 1024 * 1024); // 64 MiB

  static int lds_configured = 0;
  if (!lds_configured) {
    hipFuncSetAttribute((const void*)lstm_fused_kernel,
                        hipFuncAttributeMaxDynamicSharedMemorySize, 131072);
    lds_configured = 1;
  }

  hipLaunchKernelGGL(detect_kernel, dim3(1), dim3(64), 0, stream,
                     (const uint32_t*)x, flag);
  hipLaunchKernelGGL(wtrans_kernel, dim3(KTOT / 128, HIDN / 64, 1), dim3(256), 0, stream,
                     Wf, Wi, Wc, Wo, Wt, flag);
  hipLaunchKernelGGL(catconv_kernel, dim3(B_SZ * IN_SZ / (8 * 256), 2, 1), dim3(256), 0, stream,
                     x, h, catB, flag);
  hipLaunchKernelGGL(lstm_fused_kernel, dim3(GRID_F), dim3(512), 131072, stream,
                     Wt, catB, c, bf_, bi_, bc_, bo_, d_out, flag);
}

// Round 4
// 874.159 us; speedup vs baseline: 2.4760x; 1.0018x over previous
//
#include <hip/hip_runtime.h>
#include <stdint.h>

#define B_SZ   8192
#define IN_SZ  2048
#define HIDN   2048
#define KTOT   4096   // IN + HID
#define BKk    32
#define NKS    (KTOT / BKk)   // 128 K-steps
#define GRID_F 1024           // (8192/256) * (8192/256)

typedef __attribute__((ext_vector_type(8))) short short8;
typedef __attribute__((ext_vector_type(8))) unsigned short ushort8;
typedef __attribute__((ext_vector_type(4))) float float4v;

static __device__ __forceinline__ float bf2f(uint16_t h) {
  union { uint32_t u; float f; } v; v.u = ((uint32_t)h) << 16; return v.f;
}
static __device__ __forceinline__ uint16_t f2bf(float f) {
  union { float f; uint32_t u; } v; v.f = f;
  uint32_t r = v.u + 0x7FFFu + ((v.u >> 16) & 1u);
  return (uint16_t)(r >> 16);
}
static __device__ __forceinline__ float sigmoidf_(float v) {
  return 1.f / (1.f + __expf(-v));
}
static __device__ __forceinline__ float tanhf_(float v) {
  return 1.f - 2.f / (1.f + __expf(2.f * v));
}

static __device__ __forceinline__ ushort8 load8(const void* base, size_t eidx, int isf32) {
  ushort8 r;
  if (isf32) {
    const float* p = (const float*)base + eidx;
    float4v a = *(const float4v*)p;
    float4v b = *(const float4v*)(p + 4);
    r[0] = f2bf(a[0]); r[1] = f2bf(a[1]); r[2] = f2bf(a[2]); r[3] = f2bf(a[3]);
    r[4] = f2bf(b[0]); r[5] = f2bf(b[1]); r[6] = f2bf(b[2]); r[7] = f2bf(b[3]);
  } else {
    r = *(const ushort8*)((const uint16_t*)base + eidx);
  }
  return r;
}

// async global->LDS, 16B per lane; dest is wave-uniform base + lane*16
static __device__ __forceinline__ void gll16(const void* g, void* l) {
  __builtin_amdgcn_global_load_lds(
      (const __attribute__((address_space(1))) uint32_t*)g,
      (__attribute__((address_space(3))) uint32_t*)l, 16, 0, 0);
}

// raw barrier: no vmcnt/lgkm drain. Used ONLY in the K-loop where the only
// cross-wave LDS writers are global_load_lds DMAs ordered by counted vmcnt.
static __device__ __forceinline__ void bar() {
  asm volatile("" ::: "memory");
  __builtin_amdgcn_s_barrier();
  asm volatile("" ::: "memory");
}

// ---------------------------------------------------------------------------
// Kernel 1: MERGED prep. One dispatch replaces detect+wtrans+catconv:
//   - every block derives the dtype flag LOCALLY (wave-uniform ballot over
//     the same 512 dwords of x; identical verdict in all blocks, no dep);
//   - blocks with bid%5==0 (1024 of them) do the weight transpose
//     [K][N] -> Wt[(n*4+g)][k];  the other 4096 do cat=[x|h]->bf16 catB.
//   Interleaving 1-in-5 lets both phases run concurrently on all XCDs,
//   removing the detect->wtrans->catconv serial chain (~300us observed for
//   ~450MB of traffic).
// ---------------------------------------------------------------------------
__global__ __launch_bounds__(256) void prep_kernel(
    const void* __restrict__ x, const void* __restrict__ h,
    const void* __restrict__ Wf, const void* __restrict__ Wi,
    const void* __restrict__ Wc, const void* __restrict__ Wo,
    uint16_t* __restrict__ Wt, uint16_t* __restrict__ catB,
    int* __restrict__ flag)
{
  __shared__ uint16_t tile[4 * 64 * 128];   // 64 KB (wtrans blocks only)
  const int tid  = threadIdx.x;
  const int lane = tid & 63;

  // wave-uniform dtype detect: bf16 => exp byte of low u16 in [117,131]
  int cnt = 0;
  #pragma unroll
  for (int s = 0; s < 8; ++s) {
    uint32_t u = ((const uint32_t*)x)[lane + s * 64];
    int e = (u >> 7) & 0xFF;
    int hit = (e >= 117 && e <= 131) ? 1 : 0;
    cnt += (int)__popcll(__ballot(hit));
  }
  const int isf32 = (cnt < 256) ? 1 : 0;

  const int bid = blockIdx.x;
  if (bid == 0 && tid == 0) *flag = isf32;

  const int q = bid / 5, r5 = bid % 5;
  if (r5 == 0) {
    // ---- wtrans block q (0..1023): all 4 gates x [64 n][128 k] ----
    const int k0 = (q & 31) * 128;
    const int n0 = (q >> 5) * 64;
    const void* Wg4[4] = {Wf, Wi, Wc, Wo};

    #pragma unroll
    for (int s = 0; s < 16; ++s) {
      const int flat = s * 256 + tid;
      const int g = flat >> 10;
      const int r = (flat >> 3) & 127;      // k-local
      const int c = flat & 7;               // n-chunk
      ushort8 v = load8(Wg4[g], (size_t)(k0 + r) * HIDN + n0 + c * 8, isf32);
      // chunk-XOR swizzled transpose store: phys k-elem = (r&7)+8*((r>>3)^c)
      uint16_t* trow = tile + (g * 64 + c * 8) * 128 + (r & 7) + 8 * ((r >> 3) ^ c);
      #pragma unroll
      for (int e = 0; e < 8; ++e) trow[e * 128] = v[e];
    }
    __syncthreads();

    #pragma unroll
    for (int s = 0; s < 16; ++s) {
      const int flat = s * 256 + tid;
      const int kc = flat & 15;             // k-chunk (8 elems)
      const int np = flat >> 4;             // 0..255 == local Wt row
      const int n  = np >> 2;
      ushort8 v = *(const ushort8*)(tile + (np & 3) * 8192 + n * 128 +
                                    ((kc ^ (n >> 3)) * 8));
      *(ushort8*)(Wt + (size_t)(n0 * 4 + np) * KTOT + k0 + kc * 8) = v;
    }
  } else {
    // ---- catconv block c (0..4095): 4 rows of 2048 elems -> catB ----
    const int c    = bid - q - 1;           // bijective over non-wtrans bids
    const int half = c >> 11;               // 0: x, 1: h_prev
    const void* src = half ? h : x;
    const int row  = (c & 2047) * 4 + (tid >> 6);   // one wave per row
    #pragma unroll
    for (int s = 0; s < 4; ++s) {
      const int col = lane * 8 + s * 512;
      ushort8 v = load8(src, (size_t)row * IN_SZ + col, isf32);
      *(ushort8*)(catB + (size_t)row * KTOT + half * IN_SZ + col) = v;
    }
  }
}

// ---------------------------------------------------------------------------
// Kernel 2: fused 4-gate GEMM + LSTM epilogue. 256x256 tile, BK=32, 512 thr.
// Ring-4 LDS dbuf + counted vmcnt (T3+T4), setprio (T5), XCD-chunked grid (T1),
// K-loop LDS swizzle (T2) -- K-loop byte-identical to the verified round-3
// version. NEW: epilogue scratch XOR-swizzle. The 1.57e7 bank-conflict count
// (invariant across K-loop swizzle variants) was the epilogue scalar writes:
// fb[ml*64+ncl] has bank=f(ncl) only => 16 l15-lanes/bank = 16-way. Swizzle
// column chunk with row (c' = c ^ (row&15) @f32x4 granularity; ^(row&7)
// @bf16x8) => writer 2-way (free), reader unchanged 2-way.
// ---------------------------------------------------------------------------
extern "C" __global__ __launch_bounds__(512, 2) void lstm_fused_kernel(
    const uint16_t* __restrict__ Wt, const uint16_t* __restrict__ catB,
    const void* __restrict__ cprev,
    const void* __restrict__ bfv, const void* __restrict__ biv,
    const void* __restrict__ bcv, const void* __restrict__ bov,
    void* __restrict__ outbase, const int* __restrict__ flagp)
{
  extern __shared__ __align__(16) char ldsbuf[];   // 128 KiB dynamic

  const int isf32 = *flagp;
  const int tid  = threadIdx.x;        // 0..511
  const int lane = tid & 63;
  const int wave = tid >> 6;           // 0..7
  const int l15  = lane & 15;
  const int quad = lane >> 4;
  const int wr   = wave >> 2;          // n'-half (0,1): 128 Wt rows
  const int wc   = wave & 3;           // m-quarter (0..3): 64 catB rows

  // XCD-chunked swizzle: bid%8 = XCD; each XCD gets 4 n-tiles x 32 m-tiles.
  const int bid = blockIdx.x;
  const int xcd = bid & 7, loc = bid >> 3;        // loc 0..127
  const int nt  = xcd * 4 + (loc & 3);            // 0..31
  const int mt  = loc >> 2;                       // 0..31
  const int mB  = mt * 256;                       // catB row base
  const int nB  = nt * 256;                       // Wt row base (n' units)
  const int nb4 = nt * 64;                        // gate-col base

  // ---- staging: lane covers 16B at linear LDS offset (wave*1024 + lane*16)
  const int srow = lane >> 2;
  const int scol = ((lane & 3) ^ ((lane >> 3) & 3)) * 8;
  const uint16_t* aSrc[2];
  const uint16_t* bSrc[2];
  #pragma unroll
  for (int s = 0; s < 2; ++s) {
    aSrc[s] = Wt   + (size_t)(nB + (s * 8 + wave) * 16 + srow) * KTOT + scol;
    bSrc[s] = catB + (size_t)(mB + (s * 8 + wave) * 16 + srow) * KTOT + scol;
  }

  // ---- fragment read offsets (full-rank swizzle)
  const int rswz = (quad ^ ((l15 >> 1) & 3)) << 4;
  int offA[8], offB[4];
  #pragma unroll
  for (int i = 0; i < 8; ++i)
    offA[i] = (wr * 8 + i) * 1024 + l15 * 64 + rswz;
  #pragma unroll
  for (int j = 0; j < 4; ++j)
    offB[j] = 16384 + (wc * 4 + j) * 1024 + l15 * 64 + rswz;

  float4v acc[8][4];
  #pragma unroll
  for (int i = 0; i < 8; ++i)
    #pragma unroll
    for (int j = 0; j < 4; ++j)
      acc[i][j] = {0.f, 0.f, 0.f, 0.f};

  // prologue: stage tiles 0,1,2 (12 gll per wave); wait tile 0 (oldest 4)
  #pragma unroll
  for (int tt = 0; tt < 3; ++tt) {
    const size_t kk = (size_t)tt * BKk;
    const int bb = (tt & 3) * 32768 + wave * 1024;
    gll16(aSrc[0] + kk, ldsbuf + bb);
    gll16(aSrc[1] + kk, ldsbuf + bb + 8192);
    gll16(bSrc[0] + kk, ldsbuf + bb + 16384);
    gll16(bSrc[1] + kk, ldsbuf + bb + 16384 + 8192);
  }
  asm volatile("s_waitcnt vmcnt(8)" ::: "memory");
  bar();

#define KSTEP(T, DO_STAGE, VMSTR)                                              \
  {                                                                            \
    const int bb = ((T) & 3) * 32768;                                          \
    short8 af[4], bfr[4];                                                      \
    _Pragma("unroll")                                                          \
    for (int j = 0; j < 4; ++j)                                                \
      bfr[j] = *(const short8*)(ldsbuf + bb + offB[j]);                        \
    _Pragma("unroll")                                                          \
    for (int ii = 0; ii < 4; ++ii)                                             \
      af[ii] = *(const short8*)(ldsbuf + bb + offA[ii]);                       \
    if (DO_STAGE) {                                                            \
      const size_t kk = (size_t)((T) + 3) * BKk;                               \
      const int sb = (((T) + 3) & 3) * 32768 + wave * 1024;                    \
      gll16(aSrc[0] + kk, ldsbuf + sb);                                        \
      gll16(aSrc[1] + kk, ldsbuf + sb + 8192);                                 \
    }                                                                          \
    bar();                                                                     \
    __builtin_amdgcn_s_setprio(1);                                             \
    _Pragma("unroll")                                                          \
    for (int ii = 0; ii < 4; ++ii)                                             \
      _Pragma("unroll")                                                        \
      for (int j = 0; j < 4; ++j)                                              \
        acc[ii][j] = __builtin_amdgcn_mfma_f32_16x16x32_bf16(                  \
            af[ii], bfr[j], acc[ii][j], 0, 0, 0);                              \
    __builtin_amdgcn_s_setprio(0);                                             \
    bar();                                                                     \
    _Pragma("unroll")                                                          \
    for (int ii = 0; ii < 4; ++ii)                                             \
      af[ii] = *(const short8*)(ldsbuf + bb + offA[4 + ii]);                   \
    if (DO_STAGE) {                                                            \
      const size_t kk = (size_t)((T) + 3) * BKk;                               \
      const int sb = (((T) + 3) & 3) * 32768 + 16384 + wave * 1024;            \
      gll16(bSrc[0] + kk, ldsbuf + sb);                                        \
      gll16(bSrc[1] + kk, ldsbuf + sb + 8192);                                 \
    }                                                                          \
    asm volatile("s_waitcnt " VMSTR ::: "memory");                             \
    bar();                                                                     \
    __builtin_amdgcn_s_setprio(1);                                             \
    _Pragma("unroll")                                                          \
    for (int ii = 0; ii < 4; ++ii)                                             \
      _Pragma("unroll")                                                        \
      for (int j = 0; j < 4; ++j)                                              \
        acc[4 + ii][j] = __builtin_amdgcn_mfma_f32_16x16x32_bf16(              \
            af[ii], bfr[j], acc[4 + ii][j], 0, 0, 0);                          \
    __builtin_amdgcn_s_setprio(0);                                             \
    bar();                                                                     \
  }

  for (int t = 0; t < NKS - 3; ++t) KSTEP(t, 1, "vmcnt(8)");
  KSTEP(NKS - 3, 0, "vmcnt(4)");
  KSTEP(NKS - 2, 0, "vmcnt(0)");
  KSTEP(NKS - 1, 0, "vmcnt(0)");
#undef KSTEP

  // ---- epilogue ----
  // n' = nB + wr*128 + i*16 + quad*4 + reg; gate = reg; n = nb4 + wr*32 + i*4 + quad
  // m  = mB + wc*64 + j*16 + l15
  #pragma unroll
  for (int i = 0; i < 8; ++i) {
    const int ng = nb4 + wr * 32 + i * 4 + quad;   // 0..2047
    const float bfx = isf32 ? ((const float*)bfv)[ng] : bf2f(((const uint16_t*)bfv)[ng]);
    const float bix = isf32 ? ((const float*)biv)[ng] : bf2f(((const uint16_t*)biv)[ng]);
    const float bcx = isf32 ? ((const float*)bcv)[ng] : bf2f(((const uint16_t*)bcv)[ng]);
    const float box = isf32 ? ((const float*)bov)[ng] : bf2f(((const uint16_t*)bov)[ng]);
    #pragma unroll
    for (int j = 0; j < 4; ++j) {
      const int mg = mB + wc * 64 + j * 16 + l15;
      float4v z = acc[i][j];
      const float ft  = sigmoidf_(z[0] + bfx);
      const float it  = sigmoidf_(z[1] + bix);
      const float cto = tanhf_(z[2] + bcx);
      const float ot  = sigmoidf_(z[3] + box);
      const float cp  = isf32 ? ((const float*)cprev)[(size_t)mg * HIDN + ng]
                              : bf2f(((const uint16_t*)cprev)[(size_t)mg * HIDN + ng]);
      const float cvv = cp * ft + it * cto;
      acc[i][j][0] = ot * tanhf_(cvv);   // h
      acc[i][j][1] = cvv;                // c
    }
  }

  if (!isf32) {
    uint16_t* hout = (uint16_t*)outbase;
    uint16_t* cout = hout + (size_t)B_SZ * HIDN;
    uint16_t* hb = (uint16_t*)ldsbuf;             // [256][64], chunk8-swizzled
    uint16_t* cb = (uint16_t*)(ldsbuf + 32768);
    #pragma unroll
    for (int i = 0; i < 8; ++i) {
      const int ncl = wr * 32 + i * 4 + quad;
      #pragma unroll
      for (int j = 0; j < 4; ++j) {
        const int ml  = wc * 64 + j * 16 + l15;
        const int nph = (ncl & 7) | ((((ncl >> 3) ^ (ml & 7)) & 7) << 3);
        hb[ml * 64 + nph] = f2bf(acc[i][j][0]);
        cb[ml * 64 + nph] = f2bf(acc[i][j][1]);
      }
    }
    __syncthreads();   // full drain: ds_writes must be visible cross-wave
    #pragma unroll
    for (int s = 0; s < 4; ++s) {
      const int off = tid * 16 + s * 8192;        // within 32 KiB
      const int row = off >> 7;                   // 128 B per row (64 bf16)
      const int c8  = (off >> 4) & 7;
      const int bo  = row * 128 + ((c8 ^ (row & 7)) * 16);
      const size_t g = (size_t)(mB + row) * HIDN + nb4 + c8 * 8;
      *(ushort8*)(hout + g) = *(const ushort8*)(ldsbuf + bo);
      *(ushort8*)(cout + g) = *(const ushort8*)(ldsbuf + 32768 + bo);
    }
  } else {
    float* hout = (float*)outbase;
    float* cout = hout + (size_t)B_SZ * HIDN;
    float* fbH = (float*)ldsbuf;                  // [256][64] f32, chunk4-swz
    float* fbC = (float*)(ldsbuf + 65536);
    #pragma unroll
    for (int i = 0; i < 8; ++i) {
      const int ncl = wr * 32 + i * 4 + quad;
      #pragma unroll
      for (int j = 0; j < 4; ++j) {
        const int ml  = wc * 64 + j * 16 + l15;
        const int nph = (ncl & 3) | ((((ncl >> 2) ^ (ml & 15)) & 15) << 2);
        fbH[ml * 64 + nph] = acc[i][j][0];
        fbC[ml * 64 + nph] = acc[i][j][1];
      }
    }
    __syncthreads();   // full drain: ds_writes must be visible cross-wave
    #pragma unroll
    for (int s = 0; s < 8; ++s) {
      const int off = tid * 16 + s * 8192;        // within 64 KiB
      const int row = off >> 8;                   // 256 B per row (64 f32)
      const int c4  = (off >> 4) & 15;
      const int bo  = row * 256 + ((c4 ^ (row & 15)) * 16);
      const size_t g = (size_t)(mB + row) * HIDN + nb4 + c4 * 4;
      *(float4v*)(hout + g) = *(const float4v*)(ldsbuf + bo);
      *(float4v*)(cout + g) = *(const float4v*)(ldsbuf + 65536 + bo);
    }
  }
}

extern "C" void kernel_launch(void* const* d_in, const int* in_sizes, int n_in,
                              void* d_out, int out_size, void* d_ws, size_t ws_size,
                              hipStream_t stream) {
  const void* x   = d_in[0];
  const void* h   = d_in[1];
  const void* c   = d_in[2];
  // d_in[3] = embedding_vec, ignored in vanilla mode
  const void* Wf  = d_in[4];
  const void* Wi  = d_in[5];
  const void* Wc  = d_in[6];
  const void* Wo  = d_in[7];
  const void* bf_ = d_in[8];
  const void* bi_ = d_in[9];
  const void* bc_ = d_in[10];
  const void* bo_ = d_in[11];

  int*      flag = (int*)d_ws;
  uint16_t* Wt   = (uint16_t*)((char*)d_ws + 256);                            // 64 MiB
  uint16_t* catB = (uint16_t*)((char*)d_ws + 256 + (size_t)64 * 1024 * 1024); // 64 MiB

  static int lds_configured = 0;
  if (!lds_configured) {
    hipFuncSetAttribute((const void*)lstm_fused_kernel,
                        hipFuncAttributeMaxDynamicSharedMemorySize, 131072);
    lds_configured = 1;
  }

  hipLaunchKernelGGL(prep_kernel, dim3(5120), dim3(256), 0, stream,
                     x, h, Wf, Wi, Wc, Wo, Wt, catB, flag);
  hipLaunchKernelGGL(lstm_fused_kernel, dim3(GRID_F), dim3(512), 131072, stream,
                     Wt, catB, c, bf_, bi_, bc_, bo_, d_out, flag);
}